// Round 20
// baseline (2033.295 us; speedup 1.0000x reference)
//
#include <hip/hip_runtime.h>
#include <hip/hip_bf16.h>

#define NP   16384
#define KNN  32
#define HDIM 128
#define ODIM 64

typedef __attribute__((ext_vector_type(8))) short bf16x8;
typedef __attribute__((ext_vector_type(4))) float f32x4;

// raw barriers with counted waits (avoid __syncthreads' full vmcnt(0) drain)
#define BAR_LGKM() do { \
    asm volatile("s_waitcnt lgkmcnt(0)" ::: "memory"); \
    __builtin_amdgcn_sched_barrier(0); \
    __builtin_amdgcn_s_barrier(); \
    __builtin_amdgcn_sched_barrier(0); } while (0)
#define BAR_ALL() do { \
    asm volatile("s_waitcnt vmcnt(0) lgkmcnt(0)" ::: "memory"); \
    __builtin_amdgcn_sched_barrier(0); \
    __builtin_amdgcn_s_barrier(); \
    __builtin_amdgcn_sched_barrier(0); } while (0)

// ---------------- split fp32 -> bf16 (hi, lo) planes ----------------
__global__ __launch_bounds__(256)
void split_kernel(const float* __restrict__ X, unsigned short* __restrict__ hi,
                  unsigned short* __restrict__ lo, int n4) {
    const int i = blockIdx.x * 256 + threadIdx.x;
    if (i >= n4) return;
    const float4 v = reinterpret_cast<const float4*>(X)[i];
    const float vv[4] = {v.x, v.y, v.z, v.w};
    ushort4 h, l;
    unsigned short* hp = &h.x;
    unsigned short* lp = &l.x;
    #pragma unroll
    for (int c = 0; c < 4; ++c) {
        __hip_bfloat16 hb = __float2bfloat16(vv[c]);           // RNE
        const float hf = __bfloat162float(hb);
        __hip_bfloat16 lb = __float2bfloat16(vv[c] - hf);
        hp[c] = *reinterpret_cast<unsigned short*>(&hb);
        lp[c] = *reinterpret_cast<unsigned short*>(&lb);
    }
    reinterpret_cast<ushort4*>(hi)[i] = h;
    reinterpret_cast<ushort4*>(lo)[i] = l;
}

// split A-half of W ([HDIM][2D] -> cols 0..D-1) into bf16 hi/lo [HDIM][D]
__global__ __launch_bounds__(256)
void wsplit_kernel(const float* __restrict__ W, unsigned short* __restrict__ hi,
                   unsigned short* __restrict__ lo, int Dd) {
    const int i = blockIdx.x * 256 + threadIdx.x;
    if (i >= HDIM * Dd) return;
    const int hh = i / Dd, d = i % Dd;
    const float v = W[(size_t)hh * (2 * Dd) + d];
    __hip_bfloat16 hb = __float2bfloat16(v);
    const float hf = __bfloat162float(hb);
    __hip_bfloat16 lb = __float2bfloat16(v - hf);
    hi[i] = *reinterpret_cast<unsigned short*>(&hb);
    lo[i] = *reinterpret_cast<unsigned short*>(&lb);
}

// ---------------- squared norms (fp32, exact as before) ----------------
template<int D>
__global__ __launch_bounds__(256)
void sq_kernel(const float* __restrict__ X, float* __restrict__ sq) {
    const int lane = threadIdx.x & 63;
    const int row  = blockIdx.x * 4 + (threadIdx.x >> 6);
    float s = 0.f;
    #pragma unroll
    for (int d = lane; d < D; d += 64) {
        const float v = X[(size_t)row * D + d];
        s = fmaf(v, v, s);
    }
    #pragma unroll
    for (int off = 32; off; off >>= 1) s += __shfl_down(s, off);
    if (lane == 0) sq[row] = s;
}

// ---------------- top-32 neighbors: MFMA scores + sorted register top-k ----
// D=64: double-buffered xjB (72.3 KB, 2 blocks/CU) + raw counted barriers;
// stage(t+1) issued at tile top -> staging latency fully hidden.
// D=128: single-buffer 2-__syncthreads structure (unchanged, known-good).
template<int D>
__global__ __launch_bounds__(512, 4)
void topk_kernel(const unsigned short* __restrict__ Xhi,
                 const unsigned short* __restrict__ Xlo,
                 const float* __restrict__ sq, int* __restrict__ topIdx) {
    constexpr int TI = 16, JC = 128, SS = JC + 1;
    constexpr int NT = NP / JC;
    constexpr int KQ = D / 8;            // 16B k-groups per row
    constexpr int KS = D / 32;           // MFMA k-steps
    constexpr int PLSLOT = JC * KQ;      // 16B slots per plane
    constexpr int CALLS = 2 * PLSLOT / 512;   // global_load_lds calls per wave
    constexpr bool DBUF = (D == 64);
    constexpr int NBUF = DBUF ? 2 : 1;
    __shared__ __align__(16) unsigned short xjB[NBUF * 2 * PLSLOT * 8];
    __shared__ float scoresR[TI * SS];   // [row][col], stride 129

    const int t = threadIdx.x;
    const int lane = t & 63;
    const int waveU = __builtin_amdgcn_readfirstlane(t >> 6);
    const int rowBase = blockIdx.x * TI;
    const int l15 = lane & 15, l4 = lane >> 4;
    const float INF = __builtin_inff();
    const int jcol = 16 * waveU + l15;

    // A fragments (16 xi rows), resident in registers for the whole kernel.
    bf16x8 Ahi[KS], Alo[KS];
    #pragma unroll
    for (int s = 0; s < KS; ++s) {
        const size_t off = (size_t)(rowBase + l15) * D + 32 * s + 8 * l4;
        Ahi[s] = *reinterpret_cast<const bf16x8*>(Xhi + off);
        Alo[s] = *reinterpret_cast<const bf16x8*>(Xlo + off);
    }

    float tv[2]; int tidx[2]; float minv[2];
    #pragma unroll
    for (int r = 0; r < 2; ++r) { tv[r] = -INF; tidx[r] = 0x7fffffff; minv[r] = -INF; }

    // async staging: linear LDS slots, per-lane inverse-swizzled global src
    auto stageTile = [&](int jb, int buf) {
        #pragma unroll
        for (int c = 0; c < CALLS; ++c) {
            const int slotBase = (waveU * CALLS + c) * 64;   // wave-uniform
            const int sl = slotBase + lane;
            const int pl = sl / PLSLOT;                       // 0=hi, 1=lo
            const int ps = sl % PLSLOT;
            const int j  = ps / KQ;
            const int kq = (ps % KQ) ^ (j & (KQ - 1));        // involution
            const unsigned short* src =
                (pl ? Xlo : Xhi) + (size_t)(jb + j) * D + 8 * kq;
            __builtin_amdgcn_global_load_lds(
                (const __attribute__((address_space(1))) void*)src,
                (__attribute__((address_space(3))) void*)
                    &xjB[((size_t)buf * 2 * PLSLOT + slotBase) * 8],
                16, 0, 0);
        }
    };

    stageTile(0, 0);
    if (DBUF) { BAR_ALL(); } else { __syncthreads(); }   // tile 0 in LDS

    int cur = 0;
    for (int it = 0; it < NT; ++it) {
        const int jb = it * JC;
        const float sub0 = 0.5f * sq[jb + lane];
        const float sub1 = 0.5f * sq[jb + 64 + lane];

        if (DBUF && it + 1 < NT)
            stageTile(jb + JC, cur ^ 1);     // async into other buffer (hidden)

        // MFMA: this wave's 16 cols x 16 rows; 3 independent chains
        f32x4 Ca = {0,0,0,0}, Cb = {0,0,0,0}, Cc = {0,0,0,0};
        const size_t bufOff = (size_t)cur * 2 * PLSLOT;
        #pragma unroll
        for (int s = 0; s < KS; ++s) {
            const int kq = 4 * s + l4;
            const int slot = jcol * KQ + (kq ^ (jcol & (KQ - 1)));
            const bf16x8 Bh = *reinterpret_cast<const bf16x8*>(
                &xjB[(bufOff + slot) * 8]);
            const bf16x8 Bl = *reinterpret_cast<const bf16x8*>(
                &xjB[(bufOff + PLSLOT + slot) * 8]);
            Ca = __builtin_amdgcn_mfma_f32_16x16x32_bf16(Ahi[s], Bh, Ca, 0, 0, 0);
            Cb = __builtin_amdgcn_mfma_f32_16x16x32_bf16(Ahi[s], Bl, Cb, 0, 0, 0);
            Cc = __builtin_amdgcn_mfma_f32_16x16x32_bf16(Alo[s], Bh, Cc, 0, 0, 0);
        }
        // scatter C -> scoresR[row][col] (stride 129)
        #pragma unroll
        for (int r = 0; r < 4; ++r)
            scoresR[(4 * l4 + r) * SS + jcol] = (Ca[r] + Cb[r]) + Cc[r];

        if (DBUF) { BAR_LGKM(); }            // B1: scatter visible (no vmcnt wait)
        else {
            __syncthreads();                 // B1 (single-buffer path)
            if (it + 1 < NT) stageTile(jb + JC, 0);
        }

        // scan: sorted-insert; wave owns rows [2*waveU, 2*waveU+2)
        #pragma unroll
        for (int h = 0; h < 2; ++h) {
            float sv[2];
            unsigned long long m[2];
            #pragma unroll
            for (int r = 0; r < 2; ++r) {
                sv[r] = scoresR[(2 * waveU + r) * SS + h * 64 + lane]
                      - (h ? sub1 : sub0);
                m[r] = __ballot(sv[r] > minv[r]);
            }
            while (m[0] | m[1]) {
                #pragma unroll
                for (int r = 0; r < 2; ++r) {
                    if (m[r]) {
                        const int l = __builtin_ctzll(m[r]);  // ascending j => stable
                        m[r] &= m[r] - 1;
                        const float cv = __shfl(sv[r], l);
                        const int   cj = jb + h * 64 + l;
                        const float upv = __shfl_up(tv[r], 1);   // hoisted off chain
                        const int   upi = __shfl_up(tidx[r], 1);
                        const bool ge = (lane < KNN) && (tv[r] >= cv);
                        const int p = __popcll(__ballot(ge));    // ==32 -> no-op
                        if (lane == p)                   { tv[r] = cv;  tidx[r] = cj; }
                        else if (lane > p && lane < KNN) { tv[r] = upv; tidx[r] = upi; }
                    }
                }
            }
        }
        #pragma unroll
        for (int r = 0; r < 2; ++r)
            minv[r] = __shfl(tv[r], KNN - 1);   // exact refresh, once per tile

        if (DBUF) { BAR_ALL(); cur ^= 1; }   // B2: staging landed + scan done
        else      { __syncthreads(); }       // B2 (single-buffer path)
    }

    if (lane < KNN) {
        #pragma unroll
        for (int r = 0; r < 2; ++r)
            topIdx[(size_t)(rowBase + waveU * 2 + r) * KNN + lane] = tidx[r];
    }
}

// ---------------- gather + MLP (MFMA) + pool + out (unchanged from R19) ----
template<int D, int LAYER>
__global__ __launch_bounds__(512, 4)
void mlp_kernel(const float* __restrict__ X,
                const unsigned short* __restrict__ Xhi,
                const unsigned short* __restrict__ Xlo,
                const unsigned short* __restrict__ WAhi,
                const unsigned short* __restrict__ WAlo,
                const float* __restrict__ W, const float* __restrict__ W2,
                const int* __restrict__ topIdx, float* __restrict__ out) {
    constexpr int RPB = 2;
    constexpr int KS = D / 32;
    constexpr int W2C  = HDIM + D;
    constexpr int SPL2 = 4;
    constexpr int CL   = W2C / SPL2;
    __shared__ float AT[D * HDIM];          // B^T, for hself only
    __shared__ float xi[RPB][D];
    __shared__ float hself_s[RPB][HDIM];
    __shared__ float part[RPB][2][HDIM];    // per-kTile pooled partials
    __shared__ int   idx_s[RPB][KNN];

    const int t = threadIdx.x;
    const int lane = t & 63;
    const int waveU = __builtin_amdgcn_readfirstlane(t >> 6);
    const int rowBase = blockIdx.x * RPB;
    const int l15 = lane & 15, l4 = lane >> 4;

    if (t < RPB * D / 4) {
        const int i = t / (D / 4), dg = t % (D / 4);
        const float4 v = *reinterpret_cast<const float4*>(
            X + (size_t)(rowBase + i) * D + 4 * dg);
        xi[i][4 * dg + 0] = v.x; xi[i][4 * dg + 1] = v.y;
        xi[i][4 * dg + 2] = v.z; xi[i][4 * dg + 3] = v.w;
    }
    if (t < RPB * KNN)
        idx_s[t >> 5][t & 31] = topIdx[(size_t)(rowBase + (t >> 5)) * KNN + (t & 31)];
    bf16x8 Ahi[KS], Alo[KS];
    #pragma unroll
    for (int s = 0; s < KS; ++s) {
        const size_t off = (size_t)(waveU * 16 + l15) * D + 32 * s + 8 * l4;
        Ahi[s] = *reinterpret_cast<const bf16x8*>(WAhi + off);
        Alo[s] = *reinterpret_cast<const bf16x8*>(WAlo + off);
    }
    for (int e = t; e < HDIM * D / 4; e += 512) {
        const int hh = e % HDIM, dg = e / HDIM;
        const float4 v = *reinterpret_cast<const float4*>(
            W + (size_t)hh * (2 * D) + D + 4 * dg);          // B = W[:, D:2D]
        AT[(4 * dg + 0) * HDIM + hh] = v.x; AT[(4 * dg + 1) * HDIM + hh] = v.y;
        AT[(4 * dg + 2) * HDIM + hh] = v.z; AT[(4 * dg + 3) * HDIM + hh] = v.w;
    }
    __syncthreads();

    if (t < RPB * HDIM) {
        const int row = t >> 7, hh = t & 127;
        float s = 0.f;
        #pragma unroll 8
        for (int d = 0; d < D; ++d)
            s = fmaf(AT[d * HDIM + hh], xi[row][d], s);
        hself_s[row][hh] = s;
    }
    __syncthreads();

    #pragma unroll
    for (int a = 0; a < 4; ++a) {
        const int row = a >> 1, kT = a & 1;
        const int nIdx = idx_s[row][kT * 16 + l15];
        bf16x8 Bh[KS], Bl[KS];
        #pragma unroll
        for (int s = 0; s < KS; ++s) {
            const size_t off = (size_t)nIdx * D + 32 * s + 8 * l4;
            Bh[s] = *reinterpret_cast<const bf16x8*>(Xhi + off);
            Bl[s] = *reinterpret_cast<const bf16x8*>(Xlo + off);
        }
        f32x4 Ca = {0,0,0,0}, Cb = {0,0,0,0}, Cc = {0,0,0,0};
        #pragma unroll
        for (int s = 0; s < KS; ++s) {
            Ca = __builtin_amdgcn_mfma_f32_16x16x32_bf16(Ahi[s], Bh[s], Ca, 0, 0, 0);
            Cb = __builtin_amdgcn_mfma_f32_16x16x32_bf16(Ahi[s], Bl[s], Cb, 0, 0, 0);
            Cc = __builtin_amdgcn_mfma_f32_16x16x32_bf16(Alo[s], Bh[s], Cc, 0, 0, 0);
        }
        float ps[4];
        #pragma unroll
        for (int r = 0; r < 4; ++r) {
            const float h = (Ca[r] + Cb[r]) + Cc[r]
                          + hself_s[row][waveU * 16 + 4 * l4 + r];
            ps[r] = fminf(1.f, fmaxf(-1.f, h));
        }
        #pragma unroll
        for (int off = 1; off <= 8; off <<= 1)
            #pragma unroll
            for (int r = 0; r < 4; ++r)
                ps[r] += __shfl_xor(ps[r], off);
        if (l15 == 0)
            #pragma unroll
            for (int r = 0; r < 4; ++r)
                part[row][kT][waveU * 16 + 4 * l4 + r] = ps[r] * (1.f / KNN);
    }
    __syncthreads();

    {
        const int og   = t / SPL2;
        const int spl  = t % SPL2;
        const int orow = og >> 6, o = og & 63;
        const int c0   = spl * CL;
        float s = 0.f;
        for (int c4 = 0; c4 < CL / 4; ++c4) {
            const int c = c0 + 4 * c4;
            const float4 w = *reinterpret_cast<const float4*>(W2 + (size_t)o * W2C + c);
            float vs[4];
            if (c < HDIM) {
                const float4 q0 = *reinterpret_cast<const float4*>(&part[orow][0][c]);
                const float4 q1 = *reinterpret_cast<const float4*>(&part[orow][1][c]);
                vs[0] = q0.x + q1.x; vs[1] = q0.y + q1.y;
                vs[2] = q0.z + q1.z; vs[3] = q0.w + q1.w;
            } else {
                const float4 xv = *reinterpret_cast<const float4*>(&xi[orow][c - HDIM]);
                vs[0] = xv.x; vs[1] = xv.y; vs[2] = xv.z; vs[3] = xv.w;
            }
            const float wv[4] = {w.x, w.y, w.z, w.w};
            #pragma unroll
            for (int j = 0; j < 4; ++j)
                s = fmaf(vs[j], wv[j], s);
        }
        #pragma unroll
        for (int off = SPL2 / 2; off; off >>= 1) s += __shfl_down(s, off);
        if (spl == 0) {
            if (LAYER == 0)
                out[(size_t)(rowBase + orow) * 128 + 64 + o] = s;  // x1 cols 64..127
            else
                out[(size_t)(rowBase + orow) * ODIM + o] = s;      // final output
        }
    }
    if (LAYER == 0 && t < RPB * 64) {
        const int orow = t >> 6, d = t & 63;
        out[(size_t)(rowBase + orow) * 128 + d] = xi[orow][d];     // x1 cols 0..63
    }
}

extern "C" void kernel_launch(void* const* d_in, const int* in_sizes, int n_in,
                              void* d_out, int out_size, void* d_ws, size_t ws_size,
                              hipStream_t stream) {
    const float* x    = (const float*)d_in[0];
    const float* w0   = (const float*)d_in[1];
    const float* w2_0 = (const float*)d_in[2];
    const float* w1   = (const float*)d_in[3];
    const float* w2_1 = (const float*)d_in[4];
    float* out = (float*)d_out;

    char* ws = (char*)d_ws;
    float* sq  = (float*)ws;                                          // 64 KB
    int*   idx = (int*)(ws + (size_t)NP * 4);                         // 2 MB
    float* x1  = (float*)(ws + (size_t)NP * 4 + (size_t)NP * KNN * 4);  // 8 MB
    unsigned short* xhi = (unsigned short*)(ws + (size_t)NP * 4
                          + (size_t)NP * KNN * 4 + (size_t)NP * HDIM * 4);  // 4 MB
    unsigned short* xlo = xhi + (size_t)NP * HDIM;                    // 4 MB
    unsigned short* wa0hi = xlo + (size_t)NP * HDIM;                  // 16 KB
    unsigned short* wa0lo = wa0hi + HDIM * 64;
    unsigned short* wa1hi = wa0lo + HDIM * 64;                        // 32 KB
    unsigned short* wa1lo = wa1hi + HDIM * 128;

    // weight splits (independent of data flow)
    wsplit_kernel<<<(HDIM * 64 + 255) / 256, 256, 0, stream>>>(w0, wa0hi, wa0lo, 64);
    wsplit_kernel<<<(HDIM * 128 + 255) / 256, 256, 0, stream>>>(w1, wa1hi, wa1lo, 128);

    // layer 0 (D = 64)
    split_kernel<<<NP * 64 / 4 / 256, 256, 0, stream>>>(x, xhi, xlo, NP * 64 / 4);
    sq_kernel<64><<<NP / 4, 256, 0, stream>>>(x, sq);
    topk_kernel<64><<<NP / 16, 512, 0, stream>>>(xhi, xlo, sq, idx);
    mlp_kernel<64, 0><<<NP / 2, 512, 0, stream>>>(x, xhi, xlo, wa0hi, wa0lo,
                                                  w0, w2_0, idx, x1);

    // layer 1 (D = 128, x1 = [x, o0])
    split_kernel<<<NP * 128 / 4 / 256, 256, 0, stream>>>(x1, xhi, xlo, NP * 128 / 4);
    sq_kernel<128><<<NP / 4, 256, 0, stream>>>(x1, sq);
    topk_kernel<128><<<NP / 16, 512, 0, stream>>>(xhi, xlo, sq, idx);
    mlp_kernel<128, 1><<<NP / 2, 512, 0, stream>>>(x1, xhi, xlo, wa1hi, wa1lo,
                                                   w1, w2_1, idx, out);
}